// Round 2
// baseline (1181.553 us; speedup 1.0000x reference)
//
#include <hip/hip_runtime.h>
#include <hip/hip_bf16.h>

typedef __hip_bfloat16 bf16;

#define HWp 9216
#define Wd  96
#define Hd  96
#define Bn  8
#define Cn  256
#define IMG ((size_t)Cn * HWp)          // 2,359,296 elements per image

typedef __attribute__((ext_vector_type(8))) short  s16x8;
typedef __attribute__((ext_vector_type(8))) ushort u16x8;
typedef __attribute__((ext_vector_type(4))) float  f32x4;

// Load element i of a d_in-derived array; flag==1 -> fp32, flag==0 -> bf16.
__device__ __forceinline__ float ldf(const void* p, size_t i, int flag) {
    return flag ? ((const float*)p)[i] : __bfloat162float(((const bf16*)p)[i]);
}

// fp32 -> bf16 bits, round-to-nearest-even (finite data only).
__device__ __forceinline__ ushort bf16_rne(float f) {
    unsigned u = __float_as_uint(f);
    unsigned r = (u + 0x7fffu + ((u >> 16) & 1u)) >> 16;
    return (ushort)r;
}
__device__ __forceinline__ float bf16_hi_f(ushort h) {
    return __uint_as_float((unsigned)h << 16);
}

// ---------------------------------------------------------------------------
// Kernel 0: input dtype probe (fp32 expected; bf16 fallback kept as insurance)
// ---------------------------------------------------------------------------
__global__ void detect_dtype(const void* x, int* flag) {
    __shared__ int cnt;
    if (threadIdx.x == 0) cnt = 0;
    __syncthreads();
    const bf16* p = (const bf16*)x;
    int local = 0;
    #pragma unroll
    for (int k = 0; k < 16; ++k) {
        float w = __bfloat162float(p[threadIdx.x * 16 + k]);
        if (!(fabsf(w) < 1000.f)) local++;
    }
    atomicAdd(&cnt, local);
    __syncthreads();
    if (threadIdx.x == 0) *flag = (cnt > 64) ? 1 : 0;
}

// ---------------------------------------------------------------------------
// Kernel 1: dwconv3x3 + BN + ReLU, both branches; pixel-parallel.
// Thread = (pixel, c-group of 64). Weights broadcast from LDS. Emits HWC
// bf16 hi/lo planes for t_off, t_att and the (converted) input x itself,
// so every downstream GEMM A-operand is MFMA fragment-ready.
// ---------------------------------------------------------------------------
__global__ __launch_bounds__(256) void dwconv_bn_relu_hwc(
    const void* __restrict__ x, size_t xbase,
    const void* __restrict__ ow, const void* __restrict__ obias,
    const void* __restrict__ og, const void* __restrict__ obeta,
    const void* __restrict__ om, const void* __restrict__ ov,
    const void* __restrict__ aw, const void* __restrict__ abias,
    const void* __restrict__ ag, const void* __restrict__ abeta,
    const void* __restrict__ am, const void* __restrict__ av,
    ushort* __restrict__ tOh, ushort* __restrict__ tOl,
    ushort* __restrict__ tAh, ushort* __restrict__ tAl,
    ushort* __restrict__ Xh,  ushort* __restrict__ Xl,
    const int* __restrict__ flagp)
{
    __shared__ float sPar[256][24];   // [c]: w_o[0..8], w_a[9..17], sc_o, sh_o, sc_a, sh_a
    const int flag = *flagp;
    const int tid = threadIdx.x;

    for (int t = tid; t < 2304; t += 256) {
        int c = t / 9, k = t % 9;
        sPar[c][k]     = ldf(ow, t, flag);
        sPar[c][9 + k] = ldf(aw, t, flag);
    }
    {
        int c = tid;
        float sco = ldf(og, c, flag) * rsqrtf(ldf(ov, c, flag) + 1e-5f);
        float sca = ldf(ag, c, flag) * rsqrtf(ldf(av, c, flag) + 1e-5f);
        sPar[c][18] = sco;
        sPar[c][19] = (ldf(obias, c, flag) - ldf(om, c, flag)) * sco + ldf(obeta, c, flag);
        sPar[c][20] = sca;
        sPar[c][21] = (ldf(abias, c, flag) - ldf(am, c, flag)) * sca + ldf(abeta, c, flag);
    }
    __syncthreads();

    const int pl  = tid & 63;
    const int cg  = tid >> 6;                 // c-group: 64 channels each
    const int gpx = blockIdx.x * 64 + pl;     // chunk-local pixel (blocks never cross images)
    const int img = gpx / HWp;
    const int hw  = gpx % HWp;
    const int i   = hw / Wd, j = hw % Wd;

    int  idxk[9];
    bool mk[9];
    #pragma unroll
    for (int k = 0; k < 9; ++k) {
        int di = k / 3 - 1, dj = k % 3 - 1;
        int ii = i + di, jj = j + dj;
        mk[k]   = (ii >= 0) & (ii < Hd) & (jj >= 0) & (jj < Wd);
        idxk[k] = min(max(ii, 0), Hd - 1) * Wd + min(max(jj, 0), Wd - 1);
    }

    const size_t pbase = xbase + (size_t)img * IMG + (size_t)(cg * 64) * HWp;
    const size_t obase = (size_t)gpx * 256 + cg * 64;

    #pragma unroll 1
    for (int c8 = 0; c8 < 8; ++c8) {
        u16x8 voh, vol, vah, vAl, vxh, vxl;
        #pragma unroll
        for (int cc = 0; cc < 8; ++cc) {
            int    c = cg * 64 + c8 * 8 + cc;
            size_t b = pbase + (size_t)(c8 * 8 + cc) * HWp;
            float so = 0.f, sa = 0.f, xc = 0.f;
            #pragma unroll
            for (int k = 0; k < 9; ++k) {
                float xv = mk[k] ? ldf(x, b + idxk[k], flag) : 0.f;
                so = fmaf(xv, sPar[c][k],     so);
                sa = fmaf(xv, sPar[c][9 + k], sa);
                if (k == 4) xc = xv;
            }
            float to = fmaxf(fmaf(so, sPar[c][18], sPar[c][19]), 0.f);
            float ta = fmaxf(fmaf(sa, sPar[c][20], sPar[c][21]), 0.f);
            ushort h;
            h = bf16_rne(to); voh[cc] = h; vol[cc] = bf16_rne(to - bf16_hi_f(h));
            h = bf16_rne(ta); vah[cc] = h; vAl[cc] = bf16_rne(ta - bf16_hi_f(h));
            h = bf16_rne(xc); vxh[cc] = h; vxl[cc] = bf16_rne(xc - bf16_hi_f(h));
        }
        size_t o = obase + c8 * 8;
        *(u16x8*)(tOh + o) = voh;  *(u16x8*)(tOl + o) = vol;
        *(u16x8*)(tAh + o) = vah;  *(u16x8*)(tAl + o) = vAl;
        *(u16x8*)(Xh  + o) = vxh;  *(u16x8*)(Xl  + o) = vxl;
    }
}

// ---------------------------------------------------------------------------
// MFMA 1x1-conv GEMM, K=256, bf16x2 split (hi/lo; 3 MFMAs/k-tile -> ~18-bit
// effective input mantissa, error ~1e-5 rel).
// A: HWC bf16 planes [px][256] (hi, lo). W: d_in fp32/bf16 [COUT][256].
// Block = 256 thr = 4 waves; tile 64 px x 64 out; wave owns 16 outs x 64 px
// as 4 m-fragments of v_mfma_f32_16x16x32_bf16. No LDS, no barriers.
// Fragment layouts (m89-verified): A row = lane&15, k = (lane>>4)*8+i;
// B col = lane&15, same k; D col = lane&15, row = (lane>>4)*4+r.
// A-frag and B-frag lane layouts are mutual transposes -> swapping mfma
// operand order yields D^T: used for the CHW-output (+residual) final conv
// so stores stay coalesced along hw.
// ---------------------------------------------------------------------------
template <int COUT, int ACT, bool RES, bool OUTHWC>
__global__ __launch_bounds__(256) void gemm_mfma(
    const ushort* __restrict__ Ah, const ushort* __restrict__ Al,
    const void* __restrict__ w, const void* __restrict__ bias,
    const void* __restrict__ res, size_t res_base,
    float* __restrict__ out, const int* __restrict__ flagp)
{
    constexpr int NTO = (COUT + 63) / 64;
    const int flag = *flagp;
    const int lane = threadIdx.x & 63;
    const int wv   = threadIdx.x >> 6;
    const int ot   = blockIdx.x % NTO;     // o fastest: adjacent blocks share A tile
    const int pt   = blockIdx.x / NTO;
    const int px0  = pt * 64;
    const int ob   = ot * 64 + wv * 16;
    if (ob >= COUT) return;                // COUT=32: waves 2,3 idle (no barriers)

    const int lr = lane & 15;
    const int lk = lane >> 4;

    // ---- weight fragments, hi/lo
    s16x8 wh[8], wl[8];
    {
        const size_t wrow = (size_t)(ob + lr) * 256 + lk * 8;
        #pragma unroll
        for (int kk = 0; kk < 8; ++kk) {
            float f[8];
            if (flag) {
                float4 v0 = *(const float4*)((const float*)w + wrow + kk * 32);
                float4 v1 = *(const float4*)((const float*)w + wrow + kk * 32 + 4);
                f[0]=v0.x; f[1]=v0.y; f[2]=v0.z; f[3]=v0.w;
                f[4]=v1.x; f[5]=v1.y; f[6]=v1.z; f[7]=v1.w;
            } else {
                #pragma unroll
                for (int i = 0; i < 8; ++i)
                    f[i] = __bfloat162float(((const bf16*)w)[wrow + kk * 32 + i]);
            }
            #pragma unroll
            for (int i = 0; i < 8; ++i) {
                ushort h = bf16_rne(f[i]);
                wh[kk][i] = (short)h;
                wl[kk][i] = (short)bf16_rne(f[i] - bf16_hi_f(h));
            }
        }
    }

    f32x4 acc[4] = {};
    #pragma unroll
    for (int m = 0; m < 4; ++m) {
        const size_t arow = (size_t)(px0 + m * 16 + lr) * 256 + lk * 8;
        #pragma unroll
        for (int kk = 0; kk < 8; ++kk) {
            s16x8 ah = *(const s16x8*)(Ah + arow + kk * 32);
            s16x8 al = *(const s16x8*)(Al + arow + kk * 32);
            if (OUTHWC) {
                acc[m] = __builtin_amdgcn_mfma_f32_16x16x32_bf16(ah, wh[kk], acc[m], 0, 0, 0);
                acc[m] = __builtin_amdgcn_mfma_f32_16x16x32_bf16(ah, wl[kk], acc[m], 0, 0, 0);
                acc[m] = __builtin_amdgcn_mfma_f32_16x16x32_bf16(al, wh[kk], acc[m], 0, 0, 0);
            } else {
                acc[m] = __builtin_amdgcn_mfma_f32_16x16x32_bf16(wh[kk], ah, acc[m], 0, 0, 0);
                acc[m] = __builtin_amdgcn_mfma_f32_16x16x32_bf16(wl[kk], ah, acc[m], 0, 0, 0);
                acc[m] = __builtin_amdgcn_mfma_f32_16x16x32_bf16(wh[kk], al, acc[m], 0, 0, 0);
            }
        }
    }

    if (OUTHWC) {
        // D: row=px (lk*4+r within m-frag), col=o (lr)
        int o = ob + lr;
        float bv = ldf(bias, o, flag);
        #pragma unroll
        for (int m = 0; m < 4; ++m) {
            #pragma unroll
            for (int r = 0; r < 4; ++r) {
                int px = px0 + m * 16 + lk * 4 + r;
                float v = acc[m][r] + bv;
                if (ACT == 1) v = 1.f / (1.f + __expf(-v));
                out[(size_t)px * COUT + o] = v;
            }
        }
    } else {
        // Swapped operands: D row=o (lk*4+r), col=px (lr). CHW out + residual.
        int img = px0 / HWp;
        int hwb = px0 % HWp;
        #pragma unroll
        for (int r = 0; r < 4; ++r) {
            int o = ob + lk * 4 + r;
            float bv = ldf(bias, o, flag);
            #pragma unroll
            for (int m = 0; m < 4; ++m) {
                int hw = hwb + m * 16 + lr;
                size_t oidx = (size_t)img * IMG + (size_t)o * HWp + hw;
                float v = acc[m][r] + bv;
                if (RES) v += ldf(res, res_base + oidx, flag);
                out[oidx] = v;
            }
        }
    }
}

// ---------------------------------------------------------------------------
// Kernel 5: deformable bilinear sampling + attention sum, channel-last.
// Epilogue emits bf16 hi/lo HWC planes so the final projection runs on MFMA.
// ---------------------------------------------------------------------------
__global__ __launch_bounds__(256) void deform_sample_hwc(
    const float* __restrict__ value,
    const float* __restrict__ offset,
    const float* __restrict__ attn,
    ushort* __restrict__ outh, ushort* __restrict__ outl)
{
    __shared__ int   sIdx[16 * 32 * 4];   // [pix][n*4+p][tap]
    __shared__ float sWt [16 * 32 * 4];

    int tid  = threadIdx.x;
    int pix0 = blockIdx.x * 16;           // chunk-local pixel base

    // ---- phase 1: tap precompute --------------------------------------
    #pragma unroll
    for (int it = 0; it < 2; ++it) {
        int task = it * 256 + tid;        // 512 tasks
        int pix  = task >> 5;             // 0..15
        int np   = task & 31;             // n*4+p
        int gpix = pix0 + pix;
        int hw   = gpix % HWp;
        int i    = hw / Wd;
        int j    = hw % Wd;
        float ox = offset[(size_t)gpix * 64 + np * 2];
        float oy = offset[(size_t)gpix * 64 + np * 2 + 1];
        float a  = attn[(size_t)gpix * 32 + np];
        float ix = (float)j + 0.5f + ox * 47.5f;
        float iy = (float)i + 0.5f + oy * 47.5f;
        float x0 = floorf(ix), y0 = floorf(iy);
        float wx1 = ix - x0, wy1 = iy - y0;
        float wx0 = 1.f - wx1, wy0 = 1.f - wy1;
        int base = task * 4;
        #pragma unroll
        for (int t = 0; t < 4; ++t) {
            float xc = (t & 1) ? x0 + 1.f : x0;
            float yc = (t & 2) ? y0 + 1.f : y0;
            float wt = ((t & 1) ? wx1 : wx0) * ((t & 2) ? wy1 : wy0);
            bool ok  = (xc >= 0.f) & (xc <= 95.f) & (yc >= 0.f) & (yc <= 95.f);
            int xi = min(max((int)xc, 0), 95);
            int yi = min(max((int)yc, 0), 95);
            sIdx[base + t] = yi * Wd + xi;
            sWt [base + t] = ok ? a * wt : 0.f;
        }
    }
    __syncthreads();

    // ---- phase 2: gather + accumulate ---------------------------------
    int c   = tid;                        // 0..255
    int n   = c >> 5;                     // head
    int img = pix0 / HWp;                 // tiles never cross image
    const float* vbase = value + (size_t)img * HWp * 256;

    #pragma unroll 4
    for (int pix = 0; pix < 16; ++pix) {
        int base = (pix * 32 + n * 4) * 4;
        float acc = 0.f;
        #pragma unroll
        for (int p = 0; p < 4; ++p) {
            float4 w4 = *(const float4*)&sWt [base + p * 4];
            int4   i4 = *(const int4*)  &sIdx[base + p * 4];
            acc += w4.x * vbase[(size_t)i4.x * 256 + c];
            acc += w4.y * vbase[(size_t)i4.y * 256 + c];
            acc += w4.z * vbase[(size_t)i4.z * 256 + c];
            acc += w4.w * vbase[(size_t)i4.w * 256 + c];
        }
        ushort h = bf16_rne(acc);
        ushort l = bf16_rne(acc - bf16_hi_f(h));
        size_t o = (size_t)(pix0 + pix) * 256 + c;
        outh[o] = h;
        outl[o] = l;
    }
}

// ---------------------------------------------------------------------------
// Chunked pipeline. Per-image ws: 6 bf16 planes (tOh,tOl,tAh,tAl,Xh,Xl;
// Sh/Sl reuse tOh/tOl after step 2) + value f32 + offset f32 + attn f32
// = 41.3 MB. d_out (fp32 CHW) written only by the final kernel.
// ---------------------------------------------------------------------------
extern "C" void kernel_launch(void* const* d_in, const int* in_sizes, int n_in,
                              void* d_out, int out_size, void* d_ws, size_t ws_size,
                              hipStream_t stream)
{
    const void* x        = d_in[0];
    const void* off_dw_w = d_in[1];
    const void* off_dw_b = d_in[2];
    const void* off_bn_g = d_in[3];
    const void* off_bn_b = d_in[4];
    const void* off_bn_m = d_in[5];
    const void* off_bn_v = d_in[6];
    const void* off_pw_w = d_in[7];
    const void* off_pw_b = d_in[8];
    const void* att_dw_w = d_in[9];
    const void* att_dw_b = d_in[10];
    const void* att_bn_g = d_in[11];
    const void* att_bn_b = d_in[12];
    const void* att_bn_m = d_in[13];
    const void* att_bn_v = d_in[14];
    const void* att_pw_w = d_in[15];
    const void* att_pw_b = d_in[16];
    const void* val_w    = d_in[17];
    const void* val_b    = d_in[18];
    const void* out_w    = d_in[19];
    const void* out_b    = d_in[20];

    const size_t perImg = 6 * IMG * 2          // bf16 hi/lo planes
                        + IMG * 4              // value fp32 HWC
                        + (size_t)HWp * 64 * 4 // offset fp32 HWC
                        + (size_t)HWp * 32 * 4;// attn fp32 HWC
    int k = 1;
    if      (ws_size >= 256 + 8 * perImg) k = 8;
    else if (ws_size >= 256 + 4 * perImg) k = 4;
    else if (ws_size >= 256 + 2 * perImg) k = 2;

    char* ws = (char*)d_ws;
    int*    flag = (int*)ws;
    const size_t kIMG = (size_t)k * IMG;
    ushort* tOh = (ushort*)(ws + 256);         // also Sh after step 5
    ushort* tOl = tOh + kIMG;                  // also Sl
    ushort* tAh = tOl + kIMG;
    ushort* tAl = tAh + kIMG;
    ushort* Xh  = tAl + kIMG;
    ushort* Xl  = Xh  + kIMG;
    float*  Vf  = (float*)(Xl + kIMG);
    float*  OFF = Vf + kIMG;
    float*  ATT = OFF + (size_t)k * HWp * 64;

    detect_dtype<<<1, 256, 0, stream>>>(x, flag);

    const int nPx   = k * 144;                 // 64-px tiles
    const int nDef  = k * (HWp / 16);

    for (int b0 = 0; b0 < Bn; b0 += k) {
        size_t xelem = (size_t)b0 * IMG;
        float* outp  = (float*)d_out + xelem;

        // 1. dwconv+BN+ReLU both branches; emit t_off/t_att/x as HWC bf16x2
        dwconv_bn_relu_hwc<<<nPx, 256, 0, stream>>>(
            x, xelem,
            off_dw_w, off_dw_b, off_bn_g, off_bn_b, off_bn_m, off_bn_v,
            att_dw_w, att_dw_b, att_bn_g, att_bn_b, att_bn_m, att_bn_v,
            tOh, tOl, tAh, tAl, Xh, Xl, flag);

        // 2. offset = t_off @ off_pw^T  (64 ch, HWC fp32)
        gemm_mfma<64, 0, false, true><<<nPx, 256, 0, stream>>>(
            tOh, tOl, off_pw_w, off_pw_b, nullptr, 0, OFF, flag);

        // 3. attn = sigmoid(t_att @ att_pw^T)  (32 ch, HWC fp32)
        gemm_mfma<32, 1, false, true><<<nPx, 256, 0, stream>>>(
            tAh, tAl, att_pw_w, att_pw_b, nullptr, 0, ATT, flag);

        // 4. value = x @ val_w^T  (256 ch, HWC fp32)
        gemm_mfma<256, 0, false, true><<<nPx * 4, 256, 0, stream>>>(
            Xh, Xl, val_w, val_b, nullptr, 0, Vf, flag);

        // 5. deformable sampling + attention sum -> Sh/Sl (reuse tOh/tOl)
        deform_sample_hwc<<<nDef, 256, 0, stream>>>(Vf, OFF, ATT, tOh, tOl);

        // 6. final projection + bias + residual -> d_out (fp32 CHW)
        gemm_mfma<256, 0, true, false><<<nPx * 4, 256, 0, stream>>>(
            tOh, tOl, out_w, out_b, x, xelem, outp, flag);
    }
}